// Round 2
// baseline (561.022 us; speedup 1.0000x reference)
//
#include <hip/hip_runtime.h>
#include <math.h>

#define BN 8
#define DDIM 256
#define MEMN 131072
#define CWN 64
#define RN 4
#define CN 25
#define DELTA_C 0.005f
#define EPS_C 1e-6f
#define RPB 1024
#define NBLK (MEMN / RPB)   // 128
#define NEG_INF (-3.402823466e38f)
#define IMAX 0x7fffffff

// ---------- helpers ----------

__device__ inline void wave_reduce_max(float& v, int& i, int& t) {
#pragma unroll
  for (int off = 32; off; off >>= 1) {
    float ov = __shfl_down(v, off);
    int oi = __shfl_down(i, off);
    int ot = __shfl_down(t, off);
    if (ov > v || (ov == v && oi < i)) { v = ov; i = oi; t = ot; }
  }
}

// block of 256 threads; returns (max value, min index on tie) + winning tid
__device__ inline void block_argmax256(int tid, float v, int i, int t,
                                       float& rv, int& ri, int& rt) {
  __shared__ float sv[4];
  __shared__ int si[4], st[4];
  __shared__ float bv;
  __shared__ int bi, bt;
  wave_reduce_max(v, i, t);
  if ((tid & 63) == 0) { int w = tid >> 6; sv[w] = v; si[w] = i; st[w] = t; }
  __syncthreads();
  if (tid == 0) {
    float xv = sv[0]; int xi = si[0], xt = st[0];
#pragma unroll
    for (int w = 1; w < 4; w++)
      if (sv[w] > xv || (sv[w] == xv && si[w] < xi)) { xv = sv[w]; xi = si[w]; xt = st[w]; }
    bv = xv; bi = xi; bt = xt;
  }
  __syncthreads();
  rv = bv; ri = bi; rt = bt;
  __syncthreads();
}

// top-4 indices of 8 nonneg values padded with zero-candidates at idx 8..11
// (JAX top_k: value desc, index asc on ties)
__device__ inline void top4_of8(const float* v8, int* out4) {
  float val[12]; int idx[12]; bool used[12];
#pragma unroll
  for (int i = 0; i < 12; i++) { val[i] = (i < 8) ? v8[i] : 0.f; idx[i] = i; used[i] = false; }
  for (int r = 0; r < 4; r++) {
    int best = -1;
    for (int i = 0; i < 12; i++) {
      if (used[i]) continue;
      if (best < 0 || val[i] > val[best]) best = i;
    }
    used[best] = true;
    out4[r] = idx[best];
  }
}

// ---------- K1: MLP heads ----------
__global__ __launch_bounds__(256) void k1_heads(
    const float* __restrict__ xi,
    const float* __restrict__ Wrq, const float* __restrict__ brq,
    const float* __restrict__ Wwv, const float* __restrict__ bwv,
    const float* __restrict__ Wig, const float* __restrict__ big,
    const float* __restrict__ Wwg, const float* __restrict__ bwg,
    float* rq, float* wv, float* ig, float* wg) {
  int b = blockIdx.x, tid = threadIdx.x;
  __shared__ float x[DDIM];
  x[tid] = xi[b * DDIM + tid];
  __syncthreads();
  {
    float s = brq[tid];
    for (int d = 0; d < DDIM; d++) s = fmaf(x[d], Wrq[d * 256 + tid], s);
    rq[b * 256 + tid] = s;
  }
  if (tid < 64) {
    float s = bwv[tid];
    for (int d = 0; d < DDIM; d++) s = fmaf(x[d], Wwv[d * 64 + tid], s);
    wv[b * 64 + tid] = s;
  } else if (tid < 64 + CN) {
    int o = tid - 64;
    float s = big[o];
    for (int d = 0; d < DDIM; d++) s = fmaf(x[d], Wig[d * CN + o], s);
    ig[b * CN + o] = 1.f / (1.f + expf(-s));
  } else if (tid == 64 + CN) {
    float s = bwg[0];
    for (int d = 0; d < DDIM; d++) s = fmaf(x[d], Wwg[d], s);
    wg[b] = 1.f / (1.f + expf(-s));
  }
}

// ---------- K2: per-batch state update (scatters + link diag + fp/bp) ----------
__global__ __launch_bounds__(256) void k2_state(
    const float* __restrict__ vm, const float* __restrict__ prec,
    const float* __restrict__ rw, float* wwg, float* usage, float* memory,
    const float* __restrict__ lm, const float* __restrict__ rlm,
    const int* __restrict__ rp,
    const float* __restrict__ wv, const float* __restrict__ ig,
    const float* __restrict__ wg, int* fp, int* bp) {
  int b = blockIdx.x, tid = threadIdx.x;
  __shared__ int pos[CN];
  __shared__ float s_rw[CN], s_ww[CN], s_rel[CN], s_relnew[CN], s_imin[CN], s_wwnew[CN];
  __shared__ int s_guard[CN];
  __shared__ float minrel;
  __shared__ float fwd8[8], bwd8[8];

  if (tid < CN) {
    int p = rp[b * CN + tid];
    pos[tid] = p;
    s_rw[tid] = rw[(size_t)b * MEMN + p];
    s_ww[tid] = wwg[(size_t)b * MEMN + p];
    s_rel[tid] = usage[(size_t)b * MEMN + p];
  }
  __syncthreads();
  if (tid == 0) {
    float m = s_rel[0];
    for (int j = 1; j < CN; j++) m = fminf(m, s_rel[j]);
    minrel = m;
  }
  __syncthreads();
  if (tid < CN) {
    float u = (s_rw[tid] + s_ww[tid] > DELTA_C) ? 1.f : 0.f;
    float im = (s_rel[tid] == minrel) ? 1.f : 0.f;
    s_imin[tid] = im;
    s_relnew[tid] = u * (1.f - s_rel[tid]) + (1.f - u) * s_rel[tid];
    float igv = ig[b * CN + tid];
    s_wwnew[tid] = wg[b] * (igv * s_rw[tid] + (1.f - igv) * im);
    int g = 1;
    for (int j = tid + 1; j < CN; j++)
      if (pos[j] == pos[tid]) { g = 0; break; }
    s_guard[tid] = g;
  }
  __syncthreads();
  if (tid < CN && s_guard[tid]) {
    usage[(size_t)b * MEMN + pos[tid]] = s_relnew[tid];
    wwg[(size_t)b * MEMN + pos[tid]] = s_wwnew[tid];
  }
  // memory row scatter: 25 rows of 64
  for (int it = 0; it < 7; it++) {
    int j = it * 4 + (tid >> 6);
    int lane = tid & 63;
    if (j < CN && s_guard[j]) {
      float v = vm[((size_t)b * CN + j) * 64 + lane] * (1.f - s_imin[j]) +
                s_wwnew[j] * wv[b * 64 + lane];
      memory[((size_t)b * MEMN + pos[j]) * 64 + lane] = v;
    }
  }
  __syncthreads();
  if (tid < 8) {
    int m = tid;
    int trp_m = pos[16 + m];
    float tww = 0.f;
    for (int j = CN - 1; j >= 0; j--)
      if (pos[j] == trp_m) { tww = s_wwnew[j]; break; }  // always found at >=16+m
    float trw = rw[(size_t)b * MEMN + trp_m];
    float wwu;
    {
      int found = -1;
      for (int j = CN - 1; j >= 0; j--)
        if (pos[j] == m) { found = j; break; }
      wwu = (found >= 0) ? s_wwnew[found] : wwg[(size_t)b * MEMN + m];
    }
    float lmd = (1.f - wwu) * lm[((size_t)b * MEMN + m) * 8 + m] + wwu * prec[b * 8 + m];
    float pd = 0.f;
    for (int k = 7; k >= 0; k--)
      if (pos[16 + k] == m) { pd = prec[b * 8 + k]; break; }
    float rld = (1.f - tww) * rlm[((size_t)b * MEMN + m) * 8 + m] + tww * pd;
    fwd8[m] = lmd * trw;
    bwd8[m] = rld * trw;
  }
  __syncthreads();
  if (tid == 0) top4_of8(fwd8, &fp[b * 4]);
  if (tid == 1) top4_of8(bwd8, &bp[b * 4]);
}

// ---------- K3: heavy scan — dots + mem_sq + per-block top4 + usage argmin ----------
__global__ __launch_bounds__(256) void k3_scan(
    const float* __restrict__ memory, const float* __restrict__ usage,
    const float* __restrict__ rq,
    float* blk_sv, int* blk_si, float* blk_uv, int* blk_ui) {
  int tid = threadIdx.x;
  int b = blockIdx.x / NBLK;
  int blk = blockIdx.x % NBLK;
  int base = blk * RPB;
  __shared__ float q[4][64];
  q[tid >> 6][tid & 63] = rq[b * 256 + tid];
  __syncthreads();

  float cs[4][4];
  int ci[4][4];
#pragma unroll
  for (int r = 0; r < 4; r++)
#pragma unroll
    for (int j = 0; j < 4; j++) { cs[r][j] = NEG_INF; ci[r][j] = IMAX; }
  float uvneg = NEG_INF;
  int ui = IMAX;

  const float4* q0 = (const float4*)(&q[0][0]);
  const float4* q1 = (const float4*)(&q[1][0]);
  const float4* q2 = (const float4*)(&q[2][0]);
  const float4* q3 = (const float4*)(&q[3][0]);

#pragma unroll
  for (int rr = 0; rr < RPB / 256; rr++) {
    int m = base + rr * 256 + tid;
    const float4* row4 = (const float4*)(memory + ((size_t)b * MEMN + m) * 64);
    float ds[4] = {0.f, 0.f, 0.f, 0.f};
    float sq = 0.f;
#pragma unroll
    for (int k = 0; k < 16; k++) {
      float4 x = row4[k];
      float4 a0 = q0[k], a1 = q1[k], a2 = q2[k], a3 = q3[k];
      ds[0] = fmaf(x.x, a0.x, fmaf(x.y, a0.y, fmaf(x.z, a0.z, fmaf(x.w, a0.w, ds[0]))));
      ds[1] = fmaf(x.x, a1.x, fmaf(x.y, a1.y, fmaf(x.z, a1.z, fmaf(x.w, a1.w, ds[1]))));
      ds[2] = fmaf(x.x, a2.x, fmaf(x.y, a2.y, fmaf(x.z, a2.z, fmaf(x.w, a2.w, ds[2]))));
      ds[3] = fmaf(x.x, a3.x, fmaf(x.y, a3.y, fmaf(x.z, a3.z, fmaf(x.w, a3.w, ds[3]))));
      sq = fmaf(x.x, x.x, fmaf(x.y, x.y, fmaf(x.z, x.z, fmaf(x.w, x.w, sq))));
    }
#pragma unroll
    for (int r = 0; r < 4; r++) {
      float s = 2.f * ds[r] - sq;
      if (s > cs[r][3] || (s == cs[r][3] && m < ci[r][3])) {
        cs[r][3] = s; ci[r][3] = m;
#define CSWAP(a, bq)                                                            \
        if (cs[r][a] > cs[r][bq] || (cs[r][a] == cs[r][bq] && ci[r][a] < ci[r][bq])) { \
          float tv = cs[r][a]; cs[r][a] = cs[r][bq]; cs[r][bq] = tv;            \
          int ti = ci[r][a]; ci[r][a] = ci[r][bq]; ci[r][bq] = ti; }
        CSWAP(3, 2)
        CSWAP(2, 1)
        CSWAP(1, 0)
#undef CSWAP
      }
    }
    float u = usage[(size_t)b * MEMN + m];
    float nu = -u;
    if (nu > uvneg || (nu == uvneg && m < ui)) { uvneg = nu; ui = m; }
  }

  // block-level top-4 per r via pop-merge
#pragma unroll
  for (int r = 0; r < 4; r++) {
    for (int round = 0; round < 4; round++) {
      float rvv; int rii, rtt;
      block_argmax256(tid, cs[r][0], ci[r][0], tid, rvv, rii, rtt);
      if (tid == 0) {
        size_t o = (((size_t)b * 4 + r) * NBLK + blk) * 4 + round;
        blk_sv[o] = rvv;
        blk_si[o] = rii;
      }
      if (tid == rtt) {
        cs[r][0] = cs[r][1]; ci[r][0] = ci[r][1];
        cs[r][1] = cs[r][2]; ci[r][1] = ci[r][2];
        cs[r][2] = cs[r][3]; ci[r][2] = ci[r][3];
        cs[r][3] = NEG_INF; ci[r][3] = IMAX;
      }
    }
  }
  // usage argmin
  {
    float rvv; int rii, rtt;
    block_argmax256(tid, uvneg, ui, tid, rvv, rii, rtt);
    if (tid == 0) {
      blk_uv[b * NBLK + blk] = -rvv;
      blk_ui[b * NBLK + blk] = rii;
    }
  }
}

// ---------- K4: merge per-block results ----------
__global__ __launch_bounds__(256) void k4_merge(
    const float* __restrict__ blk_sv, const int* __restrict__ blk_si,
    const float* __restrict__ blk_uv, const int* __restrict__ blk_ui,
    int* knn, int* least) {
  int b = blockIdx.x, tid = threadIdx.x;
  for (int r = 0; r < 4; r++) {
    size_t o = (size_t)(b * 4 + r) * NBLK * 4;
    float v0 = blk_sv[o + 2 * tid], v1 = blk_sv[o + 2 * tid + 1];
    int i0 = blk_si[o + 2 * tid], i1 = blk_si[o + 2 * tid + 1];
    if (v1 > v0 || (v1 == v0 && i1 < i0)) {
      float tv = v0; v0 = v1; v1 = tv;
      int ti = i0; i0 = i1; i1 = ti;
    }
    for (int round = 0; round < 4; round++) {
      float rvv; int rii, rtt;
      block_argmax256(tid, v0, i0, tid, rvv, rii, rtt);
      if (tid == 0) knn[b * 16 + r * 4 + round] = rii;
      if (tid == rtt) { v0 = v1; i0 = i1; v1 = NEG_INF; i1 = IMAX; }
    }
  }
  // usage argmin merge
  float uv = (tid < NBLK) ? -blk_uv[b * NBLK + tid] : NEG_INF;
  int uidx = (tid < NBLK) ? blk_ui[b * NBLK + tid] : IMAX;
  float rvv; int rii, rtt;
  block_argmax256(tid, uv, uidx, tid, rvv, rii, rtt);
  if (tid == 0) least[b] = rii;
}

// ---------- K5: gather + cosine attention + output ----------
__global__ __launch_bounds__(256) void k5_attn(
    const float* __restrict__ memory, const float* __restrict__ rq,
    const int* __restrict__ knn, const int* __restrict__ fp,
    const int* __restrict__ bp, const int* __restrict__ least,
    float* out) {
  int b = blockIdx.x, tid = threadIdx.x;
  __shared__ int pos[CN];
  __shared__ float vis[CN][64];
  __shared__ float vnorm[CN];
  __shared__ float rnorm[4];
  __shared__ float sim[4][CN];
  __shared__ float pw[4][CN];
  __shared__ float qs[4][64];
  int L = least[0];
  if (tid < CN) {
    int v;
    if (tid < 16) v = knn[b * 16 + tid];
    else if (tid < 20) v = fp[b * 4 + tid - 16];
    else if (tid < 24) v = bp[b * 4 + tid - 20];
    else v = CN + 1;
    v = min(v, L);
    v = max(v, 0);
    pos[tid] = v;
  }
  qs[tid >> 6][tid & 63] = rq[b * 256 + tid];
  __syncthreads();
  for (int it = 0; it < 7; it++) {
    int j = it * 4 + (tid >> 6);
    int lane = tid & 63;
    if (j < CN) vis[j][lane] = memory[((size_t)b * MEMN + pos[j]) * 64 + lane];
  }
  __syncthreads();
  if (tid < CN) {
    float s = 0.f;
    for (int k = 0; k < 64; k++) s = fmaf(vis[tid][k], vis[tid][k], s);
    vnorm[tid] = sqrtf(s) + EPS_C;
  }
  if (tid >= 32 && tid < 36) {
    int r = tid - 32;
    float s = 0.f;
    for (int k = 0; k < 64; k++) s = fmaf(qs[r][k], qs[r][k], s);
    rnorm[r] = sqrtf(s) + EPS_C;
  }
  __syncthreads();
  if (tid < 4 * CN) {
    int r = tid / CN, c = tid % CN;
    float s = 0.f;
    for (int k = 0; k < 64; k++) s = fmaf(qs[r][k], vis[c][k], s);
    sim[r][c] = s / (rnorm[r] * vnorm[c]);
  }
  __syncthreads();
  if (tid < 4) {
    int r = tid;
    float mx = NEG_INF;
    for (int c = 0; c < CN; c++) mx = fmaxf(mx, sim[r][c]);
    float sum = 0.f;
    for (int c = 0; c < CN; c++) { float e = expf(sim[r][c] - mx); pw[r][c] = e; sum += e; }
    float inv = 1.f / sum;
    for (int c = 0; c < CN; c++) pw[r][c] *= inv;
  }
  __syncthreads();
  {
    int r = tid >> 6, w = tid & 63;
    float s = 0.f;
    for (int c = 0; c < CN; c++) s = fmaf(pw[r][c], vis[c][w], s);
    out[(size_t)b * 256 + tid] = s;
  }
}

// ---------- launch ----------
extern "C" void kernel_launch(void* const* d_in, const int* in_sizes, int n_in,
                              void* d_out, int out_size, void* d_ws, size_t ws_size,
                              hipStream_t stream) {
  const float* xi = (const float*)d_in[0];
  float* memory = (float*)d_in[1];          // updated in place (restored each launch)
  const float* vm = (const float*)d_in[2];
  const float* lm = (const float*)d_in[3];
  const float* rlm = (const float*)d_in[4];
  const float* prec = (const float*)d_in[5];
  const float* rw = (const float*)d_in[6];
  float* wwg = (float*)d_in[7];             // updated in place
  float* usage = (float*)d_in[8];           // updated in place
  // d_in[9] least_used_mem: unused by reference
  const int* rp = (const int*)d_in[10];
  const float* Wrq = (const float*)d_in[11];
  const float* brq = (const float*)d_in[12];
  const float* Wwv = (const float*)d_in[13];
  const float* bwv = (const float*)d_in[14];
  const float* Wig = (const float*)d_in[15];
  const float* big = (const float*)d_in[16];
  const float* Wwg = (const float*)d_in[17];
  const float* bwg = (const float*)d_in[18];
  float* out = (float*)d_out;

  // workspace carve (all 4B aligned)
  float* f = (float*)d_ws;
  float* rq_w = f;   f += BN * 256;
  float* wv_w = f;   f += BN * 64;
  float* ig_w = f;   f += BN * CN;
  float* wg_w = f;   f += BN;
  float* blk_sv = f; f += (size_t)BN * 4 * NBLK * 4;
  float* blk_uv = f; f += BN * NBLK;
  int* ip = (int*)f;
  int* fp_w = ip;    ip += BN * 4;
  int* bp_w = ip;    ip += BN * 4;
  int* knn_w = ip;   ip += BN * 16;
  int* least_w = ip; ip += BN;
  int* blk_si = ip;  ip += (size_t)BN * 4 * NBLK * 4;
  int* blk_ui = ip;  ip += BN * NBLK;

  hipLaunchKernelGGL(k1_heads, dim3(BN), dim3(256), 0, stream,
                     xi, Wrq, brq, Wwv, bwv, Wig, big, Wwg, bwg,
                     rq_w, wv_w, ig_w, wg_w);
  hipLaunchKernelGGL(k2_state, dim3(BN), dim3(256), 0, stream,
                     vm, prec, rw, wwg, usage, memory, lm, rlm, rp,
                     wv_w, ig_w, wg_w, fp_w, bp_w);
  hipLaunchKernelGGL(k3_scan, dim3(BN * NBLK), dim3(256), 0, stream,
                     memory, usage, rq_w, blk_sv, blk_si, blk_uv, blk_ui);
  hipLaunchKernelGGL(k4_merge, dim3(BN), dim3(256), 0, stream,
                     blk_sv, blk_si, blk_uv, blk_ui, knn_w, least_w);
  hipLaunchKernelGGL(k5_attn, dim3(BN), dim3(256), 0, stream,
                     memory, rq_w, knn_w, fp_w, bp_w, least_w, out);
}

// Round 3
// 524.492 us; speedup vs baseline: 1.0696x; 1.0696x over previous
//
#include <hip/hip_runtime.h>
#include <math.h>

#define BN 8
#define DDIM 256
#define MEMN 131072
#define CWN 64
#define RN 4
#define CN 25
#define DELTA_C 0.005f
#define EPS_C 1e-6f
#define RPB 1024
#define NBLK (MEMN / RPB)   // 128
#define NEG_INF (-3.402823466e38f)
#define IMAX 0x7fffffff

// ---------- helpers ----------

__device__ inline void wave_reduce_max(float& v, int& i, int& t) {
#pragma unroll
  for (int off = 32; off; off >>= 1) {
    float ov = __shfl_down(v, off);
    int oi = __shfl_down(i, off);
    int ot = __shfl_down(t, off);
    if (ov > v || (ov == v && oi < i)) { v = ov; i = oi; t = ot; }
  }
}

// block of 256 threads; returns (max value, min index on tie) + winning tid
__device__ inline void block_argmax256(int tid, float v, int i, int t,
                                       float& rv, int& ri, int& rt) {
  __shared__ float sv[4];
  __shared__ int si[4], st[4];
  __shared__ float bv;
  __shared__ int bi, bt;
  wave_reduce_max(v, i, t);
  if ((tid & 63) == 0) { int w = tid >> 6; sv[w] = v; si[w] = i; st[w] = t; }
  __syncthreads();
  if (tid == 0) {
    float xv = sv[0]; int xi = si[0], xt = st[0];
#pragma unroll
    for (int w = 1; w < 4; w++)
      if (sv[w] > xv || (sv[w] == xv && si[w] < xi)) { xv = sv[w]; xi = si[w]; xt = st[w]; }
    bv = xv; bi = xi; bt = xt;
  }
  __syncthreads();
  rv = bv; ri = bi; rt = bt;
  __syncthreads();
}

// top-4 indices of 8 nonneg values padded with zero-candidates at idx 8..11
// (JAX top_k: value desc, index asc on ties)
__device__ inline void top4_of8(const float* v8, int* out4) {
  float val[12]; int idx[12]; bool used[12];
#pragma unroll
  for (int i = 0; i < 12; i++) { val[i] = (i < 8) ? v8[i] : 0.f; idx[i] = i; used[i] = false; }
  for (int r = 0; r < 4; r++) {
    int best = -1;
    for (int i = 0; i < 12; i++) {
      if (used[i]) continue;
      if (best < 0 || val[i] > val[best]) best = i;
    }
    used[best] = true;
    out4[r] = idx[best];
  }
}

// ---------- K1: MLP heads ----------
__global__ __launch_bounds__(256) void k1_heads(
    const float* __restrict__ xi,
    const float* __restrict__ Wrq, const float* __restrict__ brq,
    const float* __restrict__ Wwv, const float* __restrict__ bwv,
    const float* __restrict__ Wig, const float* __restrict__ big,
    const float* __restrict__ Wwg, const float* __restrict__ bwg,
    float* rq, float* wv, float* ig, float* wg) {
  int b = blockIdx.x, tid = threadIdx.x;
  __shared__ float x[DDIM];
  x[tid] = xi[b * DDIM + tid];
  __syncthreads();
  {
    float s = brq[tid];
#pragma unroll 8
    for (int d = 0; d < DDIM; d++) s = fmaf(x[d], Wrq[d * 256 + tid], s);
    rq[b * 256 + tid] = s;
  }
  if (tid < 64) {
    float s = bwv[tid];
#pragma unroll 8
    for (int d = 0; d < DDIM; d++) s = fmaf(x[d], Wwv[d * 64 + tid], s);
    wv[b * 64 + tid] = s;
  } else if (tid < 64 + CN) {
    int o = tid - 64;
    float s = big[o];
#pragma unroll 8
    for (int d = 0; d < DDIM; d++) s = fmaf(x[d], Wig[d * CN + o], s);
    ig[b * CN + o] = 1.f / (1.f + expf(-s));
  } else if (tid == 64 + CN) {
    float s = bwg[0];
#pragma unroll 8
    for (int d = 0; d < DDIM; d++) s = fmaf(x[d], Wwg[d], s);
    wg[b] = 1.f / (1.f + expf(-s));
  }
}

// ---------- K2: per-batch state update (scatters + link diag + fp/bp) ----------
__global__ __launch_bounds__(256) void k2_state(
    const float* __restrict__ vm, const float* __restrict__ prec,
    const float* __restrict__ rw, float* wwg, float* usage, float* memory,
    const float* __restrict__ lm, const float* __restrict__ rlm,
    const int* __restrict__ rp,
    const float* __restrict__ wv, const float* __restrict__ ig,
    const float* __restrict__ wg, int* fp, int* bp) {
  int b = blockIdx.x, tid = threadIdx.x;
  __shared__ int pos[CN];
  __shared__ float s_rw[CN], s_ww[CN], s_rel[CN], s_relnew[CN], s_imin[CN], s_wwnew[CN];
  __shared__ int s_guard[CN];
  __shared__ float minrel;
  __shared__ float fwd8[8], bwd8[8];

  if (tid < CN) {
    int p = rp[b * CN + tid];
    pos[tid] = p;
    s_rw[tid] = rw[(size_t)b * MEMN + p];
    s_ww[tid] = wwg[(size_t)b * MEMN + p];
    s_rel[tid] = usage[(size_t)b * MEMN + p];
  }
  __syncthreads();
  if (tid == 0) {
    float m = s_rel[0];
    for (int j = 1; j < CN; j++) m = fminf(m, s_rel[j]);
    minrel = m;
  }
  __syncthreads();
  if (tid < CN) {
    float u = (s_rw[tid] + s_ww[tid] > DELTA_C) ? 1.f : 0.f;
    float im = (s_rel[tid] == minrel) ? 1.f : 0.f;
    s_imin[tid] = im;
    s_relnew[tid] = u * (1.f - s_rel[tid]) + (1.f - u) * s_rel[tid];
    float igv = ig[b * CN + tid];
    s_wwnew[tid] = wg[b] * (igv * s_rw[tid] + (1.f - igv) * im);
    int g = 1;
    for (int j = tid + 1; j < CN; j++)
      if (pos[j] == pos[tid]) { g = 0; break; }
    s_guard[tid] = g;
  }
  __syncthreads();
  if (tid < CN && s_guard[tid]) {
    usage[(size_t)b * MEMN + pos[tid]] = s_relnew[tid];
    wwg[(size_t)b * MEMN + pos[tid]] = s_wwnew[tid];
  }
  // memory row scatter: 25 rows of 64
  for (int it = 0; it < 7; it++) {
    int j = it * 4 + (tid >> 6);
    int lane = tid & 63;
    if (j < CN && s_guard[j]) {
      float v = vm[((size_t)b * CN + j) * 64 + lane] * (1.f - s_imin[j]) +
                s_wwnew[j] * wv[b * 64 + lane];
      memory[((size_t)b * MEMN + pos[j]) * 64 + lane] = v;
    }
  }
  __syncthreads();
  if (tid < 8) {
    int m = tid;
    int trp_m = pos[16 + m];
    float tww = 0.f;
    for (int j = CN - 1; j >= 0; j--)
      if (pos[j] == trp_m) { tww = s_wwnew[j]; break; }  // always found at >=16+m
    float trw = rw[(size_t)b * MEMN + trp_m];
    float wwu;
    {
      int found = -1;
      for (int j = CN - 1; j >= 0; j--)
        if (pos[j] == m) { found = j; break; }
      wwu = (found >= 0) ? s_wwnew[found] : wwg[(size_t)b * MEMN + m];
    }
    float lmd = (1.f - wwu) * lm[((size_t)b * MEMN + m) * 8 + m] + wwu * prec[b * 8 + m];
    float pd = 0.f;
    for (int k = 7; k >= 0; k--)
      if (pos[16 + k] == m) { pd = prec[b * 8 + k]; break; }
    float rld = (1.f - tww) * rlm[((size_t)b * MEMN + m) * 8 + m] + tww * pd;
    fwd8[m] = lmd * trw;
    bwd8[m] = rld * trw;
  }
  __syncthreads();
  if (tid == 0) top4_of8(fwd8, &fp[b * 4]);
  if (tid == 1) top4_of8(bwd8, &bp[b * 4]);
}

// ---------- K3: heavy scan — 16 lanes cooperate per row, coalesced 1KB/wave ----------
__global__ __launch_bounds__(256) void k3_scan(
    const float* __restrict__ memory, const float* __restrict__ usage,
    const float* __restrict__ rq,
    float* blk_sv, int* blk_si, float* blk_uv, int* blk_ui) {
  int tid = threadIdx.x;
  int b = blockIdx.x / NBLK;
  int blk = blockIdx.x % NBLK;
  int base = blk * RPB;
  int wave = tid >> 6, lane = tid & 63;
  int sub = lane & 15;      // chunk within row (float4 index)
  int grp = lane >> 4;      // row within group-of-4

  // q fragments: lane holds q[r][sub*4..sub*4+3] for r=0..3 (coalesced load)
  const float4* q4 = (const float4*)(rq + b * 256);
  float4 qf0 = q4[0 * 16 + sub];
  float4 qf1 = q4[1 * 16 + sub];
  float4 qf2 = q4[2 * 16 + sub];
  float4 qf3 = q4[3 * 16 + sub];

  // per-lane top-4 (valid for sub<4; query index = sub)
  float tv0 = NEG_INF, tv1 = NEG_INF, tv2 = NEG_INF, tv3 = NEG_INF;
  int ti0 = IMAX, ti1 = IMAX, ti2 = IMAX, ti3 = IMAX;

  int rowbase = base + wave * 256;   // each wave owns 256 consecutive rows
  const float4* mp = (const float4*)memory;
  size_t lanebase = ((size_t)b * MEMN + rowbase) * 16 + (size_t)grp * 16 + sub;

#pragma unroll 4
  for (int it = 0; it < 64; it++) {
    int m = rowbase + it * 4 + grp;
    float4 x = mp[lanebase + (size_t)it * 64];
    float d0 = fmaf(x.x, qf0.x, fmaf(x.y, qf0.y, fmaf(x.z, qf0.z, x.w * qf0.w)));
    float d1 = fmaf(x.x, qf1.x, fmaf(x.y, qf1.y, fmaf(x.z, qf1.z, x.w * qf1.w)));
    float d2 = fmaf(x.x, qf2.x, fmaf(x.y, qf2.y, fmaf(x.z, qf2.z, x.w * qf2.w)));
    float d3 = fmaf(x.x, qf3.x, fmaf(x.y, qf3.y, fmaf(x.z, qf3.z, x.w * qf3.w)));
    float sq = fmaf(x.x, x.x, fmaf(x.y, x.y, fmaf(x.z, x.z, x.w * x.w)));
    // butterfly reduce over the 16-lane sub-group
#pragma unroll
    for (int off = 1; off < 16; off <<= 1) {
      d0 += __shfl_xor(d0, off);
      d1 += __shfl_xor(d1, off);
      d2 += __shfl_xor(d2, off);
      d3 += __shfl_xor(d3, off);
      sq += __shfl_xor(sq, off);
    }
    // lanes sub<4 insert score for query==sub into their top-4 list
    float d = (sub == 0) ? d0 : (sub == 1) ? d1 : (sub == 2) ? d2 : d3;
    float s = 2.f * d - sq;
    if (sub < 4) {
      if (s > tv3) {
        tv3 = s; ti3 = m;
        if (tv3 > tv2) { float t = tv2; tv2 = tv3; tv3 = t; int u = ti2; ti2 = ti3; ti3 = u; }
        if (tv2 > tv1) { float t = tv1; tv1 = tv2; tv2 = t; int u = ti1; ti1 = ti2; ti2 = u; }
        if (tv1 > tv0) { float t = tv0; tv0 = tv1; tv1 = t; int u = ti0; ti0 = ti1; ti1 = u; }
      }
    }
  }

  // dump per-lane lists: 16 lists per query (4 waves x 4 groups)
  __shared__ float lsv[4][16][4];
  __shared__ int lsi[4][16][4];
  if (sub < 4) {
    int slot = wave * 4 + grp;
    lsv[sub][slot][0] = tv0; lsi[sub][slot][0] = ti0;
    lsv[sub][slot][1] = tv1; lsi[sub][slot][1] = ti1;
    lsv[sub][slot][2] = tv2; lsi[sub][slot][2] = ti2;
    lsv[sub][slot][3] = tv3; lsi[sub][slot][3] = ti3;
  }
  __syncthreads();
  if (tid < 4) {
    int r = tid;
    size_t o = (((size_t)b * 4 + r) * NBLK + blk) * 4;
    for (int round = 0; round < 4; round++) {
      float bv = NEG_INF; int bi = IMAX; int bslot = 0, bj = 0;
      for (int e = 0; e < 64; e++) {
        int sl = e >> 2, j = e & 3;
        float v = lsv[r][sl][j];
        int ix = lsi[r][sl][j];
        if (v > bv || (v == bv && ix < bi)) { bv = v; bi = ix; bslot = sl; bj = j; }
      }
      lsv[r][bslot][bj] = NEG_INF;
      blk_sv[o + round] = bv;
      blk_si[o + round] = bi;
    }
  }

  // usage argmin: fully coalesced float4-per-thread scan of this block's rows
  {
    const float4* u4 = (const float4*)(usage + (size_t)b * MEMN + base);
    float4 uu = u4[tid];
    int mb = base + tid * 4;
    float uv = uu.x; int uix = mb;
    if (uu.y < uv) { uv = uu.y; uix = mb + 1; }
    if (uu.z < uv) { uv = uu.z; uix = mb + 2; }
    if (uu.w < uv) { uv = uu.w; uix = mb + 3; }
    float rvv; int rii, rtt;
    block_argmax256(tid, -uv, uix, tid, rvv, rii, rtt);
    if (tid == 0) {
      blk_uv[b * NBLK + blk] = -rvv;
      blk_ui[b * NBLK + blk] = rii;
    }
  }
}

// ---------- K4: merge per-block results ----------
__global__ __launch_bounds__(256) void k4_merge(
    const float* __restrict__ blk_sv, const int* __restrict__ blk_si,
    const float* __restrict__ blk_uv, const int* __restrict__ blk_ui,
    int* knn, int* least) {
  int b = blockIdx.x, tid = threadIdx.x;
  for (int r = 0; r < 4; r++) {
    size_t o = (size_t)(b * 4 + r) * NBLK * 4;
    float v0 = blk_sv[o + 2 * tid], v1 = blk_sv[o + 2 * tid + 1];
    int i0 = blk_si[o + 2 * tid], i1 = blk_si[o + 2 * tid + 1];
    if (v1 > v0 || (v1 == v0 && i1 < i0)) {
      float tv = v0; v0 = v1; v1 = tv;
      int ti = i0; i0 = i1; i1 = ti;
    }
    for (int round = 0; round < 4; round++) {
      float rvv; int rii, rtt;
      block_argmax256(tid, v0, i0, tid, rvv, rii, rtt);
      if (tid == 0) knn[b * 16 + r * 4 + round] = rii;
      if (tid == rtt) { v0 = v1; i0 = i1; v1 = NEG_INF; i1 = IMAX; }
    }
  }
  // usage argmin merge
  float uv = (tid < NBLK) ? -blk_uv[b * NBLK + tid] : NEG_INF;
  int uidx = (tid < NBLK) ? blk_ui[b * NBLK + tid] : IMAX;
  float rvv; int rii, rtt;
  block_argmax256(tid, uv, uidx, tid, rvv, rii, rtt);
  if (tid == 0) least[b] = rii;
}

// ---------- K5: gather + cosine attention + output ----------
__global__ __launch_bounds__(256) void k5_attn(
    const float* __restrict__ memory, const float* __restrict__ rq,
    const int* __restrict__ knn, const int* __restrict__ fp,
    const int* __restrict__ bp, const int* __restrict__ least,
    float* out) {
  int b = blockIdx.x, tid = threadIdx.x;
  __shared__ int pos[CN];
  __shared__ float vis[CN][64];
  __shared__ float vnorm[CN];
  __shared__ float rnorm[4];
  __shared__ float sim[4][CN];
  __shared__ float pw[4][CN];
  __shared__ float qs[4][64];
  int L = least[0];
  if (tid < CN) {
    int v;
    if (tid < 16) v = knn[b * 16 + tid];
    else if (tid < 20) v = fp[b * 4 + tid - 16];
    else if (tid < 24) v = bp[b * 4 + tid - 20];
    else v = CN + 1;
    v = min(v, L);
    v = max(v, 0);
    pos[tid] = v;
  }
  qs[tid >> 6][tid & 63] = rq[b * 256 + tid];
  __syncthreads();
  for (int it = 0; it < 7; it++) {
    int j = it * 4 + (tid >> 6);
    int lane = tid & 63;
    if (j < CN) vis[j][lane] = memory[((size_t)b * MEMN + pos[j]) * 64 + lane];
  }
  __syncthreads();
  if (tid < CN) {
    float s = 0.f;
    for (int k = 0; k < 64; k++) s = fmaf(vis[tid][k], vis[tid][k], s);
    vnorm[tid] = sqrtf(s) + EPS_C;
  }
  if (tid >= 32 && tid < 36) {
    int r = tid - 32;
    float s = 0.f;
    for (int k = 0; k < 64; k++) s = fmaf(qs[r][k], qs[r][k], s);
    rnorm[r] = sqrtf(s) + EPS_C;
  }
  __syncthreads();
  if (tid < 4 * CN) {
    int r = tid / CN, c = tid % CN;
    float s = 0.f;
    for (int k = 0; k < 64; k++) s = fmaf(qs[r][k], vis[c][k], s);
    sim[r][c] = s / (rnorm[r] * vnorm[c]);
  }
  __syncthreads();
  if (tid < 4) {
    int r = tid;
    float mx = NEG_INF;
    for (int c = 0; c < CN; c++) mx = fmaxf(mx, sim[r][c]);
    float sum = 0.f;
    for (int c = 0; c < CN; c++) { float e = expf(sim[r][c] - mx); pw[r][c] = e; sum += e; }
    float inv = 1.f / sum;
    for (int c = 0; c < CN; c++) pw[r][c] *= inv;
  }
  __syncthreads();
  {
    int r = tid >> 6, w = tid & 63;
    float s = 0.f;
    for (int c = 0; c < CN; c++) s = fmaf(pw[r][c], vis[c][w], s);
    out[(size_t)b * 256 + tid] = s;
  }
}

// ---------- launch ----------
extern "C" void kernel_launch(void* const* d_in, const int* in_sizes, int n_in,
                              void* d_out, int out_size, void* d_ws, size_t ws_size,
                              hipStream_t stream) {
  const float* xi = (const float*)d_in[0];
  float* memory = (float*)d_in[1];          // updated in place (restored each launch)
  const float* vm = (const float*)d_in[2];
  const float* lm = (const float*)d_in[3];
  const float* rlm = (const float*)d_in[4];
  const float* prec = (const float*)d_in[5];
  const float* rw = (const float*)d_in[6];
  float* wwg = (float*)d_in[7];             // updated in place
  float* usage = (float*)d_in[8];           // updated in place
  // d_in[9] least_used_mem: unused by reference
  const int* rp = (const int*)d_in[10];
  const float* Wrq = (const float*)d_in[11];
  const float* brq = (const float*)d_in[12];
  const float* Wwv = (const float*)d_in[13];
  const float* bwv = (const float*)d_in[14];
  const float* Wig = (const float*)d_in[15];
  const float* big = (const float*)d_in[16];
  const float* Wwg = (const float*)d_in[17];
  const float* bwg = (const float*)d_in[18];
  float* out = (float*)d_out;

  // workspace carve (all 4B aligned)
  float* f = (float*)d_ws;
  float* rq_w = f;   f += BN * 256;
  float* wv_w = f;   f += BN * 64;
  float* ig_w = f;   f += BN * CN;
  float* wg_w = f;   f += BN;
  float* blk_sv = f; f += (size_t)BN * 4 * NBLK * 4;
  float* blk_uv = f; f += BN * NBLK;
  int* ip = (int*)f;
  int* fp_w = ip;    ip += BN * 4;
  int* bp_w = ip;    ip += BN * 4;
  int* knn_w = ip;   ip += BN * 16;
  int* least_w = ip; ip += BN;
  int* blk_si = ip;  ip += (size_t)BN * 4 * NBLK * 4;
  int* blk_ui = ip;  ip += BN * NBLK;

  hipLaunchKernelGGL(k1_heads, dim3(BN), dim3(256), 0, stream,
                     xi, Wrq, brq, Wwv, bwv, Wig, big, Wwg, bwg,
                     rq_w, wv_w, ig_w, wg_w);
  hipLaunchKernelGGL(k2_state, dim3(BN), dim3(256), 0, stream,
                     vm, prec, rw, wwg, usage, memory, lm, rlm, rp,
                     wv_w, ig_w, wg_w, fp_w, bp_w);
  hipLaunchKernelGGL(k3_scan, dim3(BN * NBLK), dim3(256), 0, stream,
                     memory, usage, rq_w, blk_sv, blk_si, blk_uv, blk_ui);
  hipLaunchKernelGGL(k4_merge, dim3(BN), dim3(256), 0, stream,
                     blk_sv, blk_si, blk_uv, blk_ui, knn_w, least_w);
  hipLaunchKernelGGL(k5_attn, dim3(BN), dim3(256), 0, stream,
                     memory, rq_w, knn_w, fp_w, bp_w, least_w, out);
}